// Round 14
// baseline (86.900 us; speedup 1.0000x reference)
//
#include <hip/hip_runtime.h>
#include <cstddef>
#include <cstdint>

#define NROWS  200000
#define CIN    32
#define COUT   64
#define KV     27
#define NK0    14                      // wave-half 0: k = 0..13
#define NK1    13                      // wave-half 1: k = 14..26
#define NTILES (NROWS / 64)            // 3125 tiles of 64 rows

typedef __attribute__((ext_vector_type(8))) short  short8;
typedef __attribute__((ext_vector_type(4))) float  f32x4;

// RNE float -> bf16 (inputs finite)
__device__ __forceinline__ unsigned short f2bf(float x) {
  unsigned u = __builtin_bit_cast(unsigned, x);
  u += 0x7FFFu + ((u >> 16) & 1u);
  return (unsigned short)(u >> 16);
}

// Pack weight [27][32][64] f32 -> bf16 B-fragments, mfma_16x16x32 B layout:
// wsB[(k*4+t)*64 + lane][f] = W[k][(lane>>4)*8+f][t*16+(lane&15)]
__global__ void prep_weight_kernel(const float* __restrict__ w,
                                   short8* __restrict__ wsB) {
  int tid = blockIdx.x * blockDim.x + threadIdx.x;   // 27*4*64 = 6912
  if (tid >= KV * 4 * 64) return;
  int lane = tid & 63;
  int t    = (tid >> 6) & 3;
  int k    = tid >> 8;
  int col  = t * 16 + (lane & 15);
  int kin0 = (lane >> 4) * 8;
  short8 v;
#pragma unroll
  for (int f = 0; f < 8; ++f)
    v[f] = (short)f2bf(w[((size_t)k * CIN + kin0 + f) * COUT + col]);
  wsB[tid] = v;
}

// feats f32 [N][32] -> bf16 [N+1][32]; row N (pad) = zeros.
__global__ void prep_feats_kernel(const float* __restrict__ feats,
                                  short8* __restrict__ fb) {
  int i = blockIdx.x * blockDim.x + threadIdx.x;
  const int total8 = (NROWS + 1) * CIN / 8;          // 800004
  if (i >= total8) return;
  short8 v = {0, 0, 0, 0, 0, 0, 0, 0};
  if (i < NROWS * CIN / 8) {
    const f32x4* p = (const f32x4*)feats + (size_t)i * 2;
    f32x4 a = p[0], b = p[1];
#pragma unroll
    for (int f = 0; f < 4; ++f) {
      v[f]     = (short)f2bf(a[f]);
      v[4 + f] = (short)f2bf(b[f]);
    }
  }
  fb[i] = v;
}

// Main: SPLIT-K over the champion wave. Each 64-row tile is handled by TWO
// waves: half 0 does k=0..13 (+bias), half 1 does k=14..26. Identical
// per-wave structure to the 47us champion (Mw=4, idx-LDS, compiler-scheduled
// loop, same B-load and store pattern) -> no B/store side-effects (the
// confounds that sank R8/R13). Waves double to 6250 (1563 blocks, 6.1
// blocks/CU oversubscription; 16 waves/CU static) and the per-wave serial
// chain halves -> attacks the measured concurrency deficit (7 resident vs
// 12.2 offered). End: partner-half accumulator exchange via LDS (each wave
// ships 2 of its 4 m-tiles, 8 KB; 2 barriers); each wave stores 2 m-tiles.
__global__ __launch_bounds__(256, 4)
void spconv_mfma_kernel(const unsigned short* __restrict__ featsbf,
                        const short8* __restrict__ wsB,
                        const float* __restrict__ bias,
                        const int* __restrict__ in_idx,
                        float* __restrict__ out) {
  // 32 KB: reduction buffer [pair][half][j(m-sub)][t][lane]; the idx staging
  // area (4 waves x 14 x 64 ints = 14,336 B) aliases over it (disjoint in
  // time, separated by the first __syncthreads after the k-loops).
  __shared__ f32x4 sRed[2][2][2][4][64];
  int* sIdxAll = (int*)&sRed[0][0][0][0][0];

  const int tid  = threadIdx.x;
  const int lane = tid & 63;
  const int w    = tid >> 6;
  const int pr   = w >> 1;                           // pair = tile slot
  const int di   = w & 1;                            // k-half
  int tile = (int)blockIdx.x * 2 + pr;
  if (tile > NTILES - 1) tile = NTILES - 1;          // clamp: dup stores of
  const int row0 = tile << 6;                        // identical values, benign
  const int nk    = di ? NK1 : NK0;
  const int kbase = di ? NK0 : 0;

  int* sIdxW = sIdxAll + w * (NK0 * 64);

  // ---- stage this wave's k-half idx block (fully unrolled per half) ----
  if (di == 0) {
    int tmp[NK0];
#pragma unroll
    for (int k = 0; k < NK0; ++k)
      tmp[k] = in_idx[(size_t)k * NROWS + row0 + lane];
#pragma unroll
    for (int k = 0; k < NK0; ++k) sIdxW[k * 64 + lane] = tmp[k];
  } else {
    int tmp[NK1];
#pragma unroll
    for (int k = 0; k < NK1; ++k)
      tmp[k] = in_idx[(size_t)(NK0 + k) * NROWS + row0 + lane];
#pragma unroll
    for (int k = 0; k < NK1; ++k) sIdxW[k * 64 + lane] = tmp[k];
  }

  const int c16  = lane & 15;
  const int kg   = lane >> 4;
  const int koff = kg * 8;

  f32x4 acc[4][4];                                   // [m][t]
#pragma unroll
  for (int t = 0; t < 4; ++t) {
    float bv = (di == 0) ? bias[t * 16 + c16] : 0.0f;
    f32x4 bvv = {bv, bv, bv, bv};
#pragma unroll
    for (int m = 0; m < 4; ++m) acc[m][t] = bvv;
  }

  const short8* bp = wsB + (size_t)kbase * 256 + lane;

  // idx for kk=0 (broadcast ds_read across kg groups)
  int idxc[4], idxn[4];
#pragma unroll
  for (int m = 0; m < 4; ++m) idxc[m] = sIdxW[m * 16 + c16];

  for (int kk = 0; kk < nk; ++kk) {
    const int knn = (kk + 1 < nk) ? kk + 1 : nk - 1;
#pragma unroll
    for (int m = 0; m < 4; ++m) idxn[m] = sIdxW[knn * 64 + m * 16 + c16];

    short8 bfr[4];
#pragma unroll
    for (int t = 0; t < 4; ++t) bfr[t] = bp[(kk * 4 + t) * 64];

    short8 afr[4];
#pragma unroll
    for (int m = 0; m < 4; ++m)
      afr[m] = *(const short8*)(featsbf + (size_t)idxc[m] * CIN + koff);

#pragma unroll
    for (int m = 0; m < 4; ++m) {
      acc[m][0] = __builtin_amdgcn_mfma_f32_16x16x32_bf16(afr[m], bfr[0], acc[m][0], 0, 0, 0);
      acc[m][1] = __builtin_amdgcn_mfma_f32_16x16x32_bf16(afr[m], bfr[1], acc[m][1], 0, 0, 0);
      acc[m][2] = __builtin_amdgcn_mfma_f32_16x16x32_bf16(afr[m], bfr[2], acc[m][2], 0, 0, 0);
      acc[m][3] = __builtin_amdgcn_mfma_f32_16x16x32_bf16(afr[m], bfr[3], acc[m][3], 0, 0, 0);
    }

#pragma unroll
    for (int m = 0; m < 4; ++m) idxc[m] = idxn[m];
  }

  // ---- partner-half exchange ----
  __syncthreads();                                   // idx reads done; sRed safe
  const int mw0 = di ? 0 : 2;                        // m-tiles shipped out
#pragma unroll
  for (int j = 0; j < 2; ++j)
#pragma unroll
    for (int t = 0; t < 4; ++t)
      sRed[pr][di][j][t][lane] = acc[mw0 + j][t];
  __syncthreads();

  const int ms0 = di ? 2 : 0;                        // m-tiles this wave stores
#pragma unroll
  for (int j = 0; j < 2; ++j) {
#pragma unroll
    for (int t = 0; t < 4; ++t) {
      f32x4 s = acc[ms0 + j][t] + sRed[pr][1 - di][j][t][lane];
#pragma unroll
      for (int r = 0; r < 4; ++r)
        out[(size_t)(row0 + (ms0 + j) * 16 + kg * 4 + r) * COUT + t * 16 + c16] = s[r];
    }
  }
}

// Correct-but-slow fallback if ws is tiny (shouldn't happen).
__global__ void spconv_naive_kernel(const float* __restrict__ feats,
                                    const float* __restrict__ w,
                                    const float* __restrict__ bias,
                                    const int* __restrict__ in_idx,
                                    float* __restrict__ out) {
  int gid = blockIdx.x * blockDim.x + threadIdx.x;
  if (gid >= NROWS * COUT) return;
  int row = gid / COUT, co = gid % COUT;
  float acc = bias[co];
  for (int k = 0; k < KV; ++k) {
    int idx = in_idx[(size_t)k * NROWS + row];
    if (idx < NROWS) {
      const float* fr = feats + (size_t)idx * CIN;
      const float* wk = w + (size_t)k * CIN * COUT + co;
#pragma unroll
      for (int c = 0; c < CIN; ++c) acc += fr[c] * wk[(size_t)c * COUT];
    }
  }
  out[gid] = acc;
}

extern "C" void kernel_launch(void* const* d_in, const int* in_sizes, int n_in,
                              void* d_out, int out_size, void* d_ws, size_t ws_size,
                              hipStream_t stream) {
  const float* feats  = (const float*)d_in[0];
  const float* weight = (const float*)d_in[1];
  const float* bias   = (const float*)d_in[2];
  const int*   in_idx = (const int*)d_in[3];
  float*       out    = (float*)d_out;

  const size_t wsB_bytes = (size_t)KV * 4 * 64 * 16;        // 110592
  const size_t fb_bytes  = (size_t)(NROWS + 1) * CIN * 2;   // 12800064
  short8*         wsB     = (short8*)d_ws;
  unsigned short* featsbf = (unsigned short*)((char*)d_ws + wsB_bytes);

  if (ws_size >= wsB_bytes + fb_bytes) {
    prep_weight_kernel<<<27, 256, 0, stream>>>(weight, wsB);
    prep_feats_kernel<<<((NROWS + 1) * CIN / 8 + 255) / 256, 256, 0, stream>>>(
        feats, (short8*)featsbf);
    const int blocks = (NTILES + 1) / 2;                     // 1563
    spconv_mfma_kernel<<<blocks, 256, 0, stream>>>(
        featsbf, wsB, bias, in_idx, out);
  } else {
    spconv_naive_kernel<<<(NROWS * COUT + 255) / 256, 256, 0, stream>>>(
        feats, weight, bias, in_idx, out);
  }
}

// Round 15
// 75.952 us; speedup vs baseline: 1.1442x; 1.1442x over previous
//
#include <hip/hip_runtime.h>
#include <cstddef>
#include <cstdint>

#define NROWS  200000
#define CIN    32
#define COUT   64
#define KV     27
#define NWAVES (NROWS / 64)   // 3125

typedef __attribute__((ext_vector_type(8))) short  short8;
typedef __attribute__((ext_vector_type(4))) float  f32x4;

// RNE float -> bf16 (inputs finite)
__device__ __forceinline__ unsigned short f2bf(float x) {
  unsigned u = __builtin_bit_cast(unsigned, x);
  u += 0x7FFFu + ((u >> 16) & 1u);
  return (unsigned short)(u >> 16);
}

// Pack weight [27][32][64] f32 -> bf16 B-fragments, mfma_16x16x32 B layout:
// wsB[(k*4+t)*64 + lane][f] = W[k][(lane>>4)*8+f][t*16+(lane&15)]
__global__ void prep_weight_kernel(const float* __restrict__ w,
                                   short8* __restrict__ wsB) {
  int tid = blockIdx.x * blockDim.x + threadIdx.x;   // 27*4*64 = 6912
  if (tid >= KV * 4 * 64) return;
  int lane = tid & 63;
  int t    = (tid >> 6) & 3;
  int k    = tid >> 8;
  int col  = t * 16 + (lane & 15);
  int kin0 = (lane >> 4) * 8;
  short8 v;
#pragma unroll
  for (int f = 0; f < 8; ++f)
    v[f] = (short)f2bf(w[((size_t)k * CIN + kin0 + f) * COUT + col]);
  wsB[tid] = v;
}

// Main: exact R5 champion skeleton (Mw=4, idx staged via LDS, 256-thread
// blocks, compiler-scheduled k-loop) with the feats PRE-CONVERSION PASS
// ELIMINATED: gather fp32 feats directly, convert f32->bf16 in-register.
// Pad handling by per-lane predication (idx < NROWS): exec-masked lanes
// issue NO memory transaction (the 80% pad traffic vanishes entirely) and
// keep a zeroed A-fragment. Each lane's 32 B (kg*32 offset into the 128 B
// row) sits inside one 64 B line, so transactions/real-row = 1 line still.
// Saves the 38 MB / ~8 us prep_feats kernel + one launch; main grows only
// slightly (R11 showed vmem-volume deltas of this scale are absorbed).
__global__ __launch_bounds__(256, 4)
void spconv_mfma_kernel(const float* __restrict__ feats,
                        const short8* __restrict__ wsB,
                        const float* __restrict__ bias,
                        const int* __restrict__ in_idx,
                        float* __restrict__ out) {
  __shared__ int sIdx[4][KV][64];                    // 27,648 B

  const int tid  = threadIdx.x;
  const int lane = tid & 63;
  const int w    = tid >> 6;
  const int wid  = (int)blockIdx.x * 4 + w;
  if (wid >= NWAVES) return;
  const int row0 = wid << 6;

  // ---- stage this wave's idx block into LDS (per-wave region, no barrier) --
  {
    int tmp[KV];
#pragma unroll
    for (int k = 0; k < KV; ++k)
      tmp[k] = in_idx[(size_t)k * NROWS + row0 + lane];
#pragma unroll
    for (int k = 0; k < KV; ++k)
      sIdx[w][k][lane] = tmp[k];
  }

  const int c16  = lane & 15;
  const int kg   = lane >> 4;
  const int koff = kg * 8;                           // float offset in row

  f32x4 acc[4][4];                                   // [m][t]
#pragma unroll
  for (int t = 0; t < 4; ++t) {
    float bv = bias[t * 16 + c16];
    f32x4 bvv = {bv, bv, bv, bv};
#pragma unroll
    for (int m = 0; m < 4; ++m) acc[m][t] = bvv;
  }

  const short8* bp = wsB + lane;

  // idx for k=0 (broadcast ds_read: 4 lanes same address -> free)
  int idxc[4], idxn[4];
#pragma unroll
  for (int m = 0; m < 4; ++m) idxc[m] = sIdx[w][0][m * 16 + c16];

  for (int k = 0; k < KV; ++k) {
    // prefetch idx(k+1) from LDS (off the global-latency path entirely)
    const int kn = (k + 1 < KV) ? k + 1 : KV - 1;
#pragma unroll
    for (int m = 0; m < 4; ++m) idxn[m] = sIdx[w][kn][m * 16 + c16];

    short8 bfr[4];
#pragma unroll
    for (int t = 0; t < 4; ++t) bfr[t] = bp[(k * 4 + t) * 64];

    short8 afr[4];
#pragma unroll
    for (int m = 0; m < 4; ++m) {
      short8 a = {0, 0, 0, 0, 0, 0, 0, 0};
      const int id = idxc[m];
      if (id < NROWS) {                              // pad lanes: masked off
        const f32x4* p = (const f32x4*)(feats + (size_t)id * CIN + koff);
        f32x4 x = p[0], y = p[1];
#pragma unroll
        for (int f = 0; f < 4; ++f) {
          a[f]     = (short)f2bf(x[f]);
          a[4 + f] = (short)f2bf(y[f]);
        }
      }
      afr[m] = a;
    }

#pragma unroll
    for (int m = 0; m < 4; ++m) {
      acc[m][0] = __builtin_amdgcn_mfma_f32_16x16x32_bf16(afr[m], bfr[0], acc[m][0], 0, 0, 0);
      acc[m][1] = __builtin_amdgcn_mfma_f32_16x16x32_bf16(afr[m], bfr[1], acc[m][1], 0, 0, 0);
      acc[m][2] = __builtin_amdgcn_mfma_f32_16x16x32_bf16(afr[m], bfr[2], acc[m][2], 0, 0, 0);
      acc[m][3] = __builtin_amdgcn_mfma_f32_16x16x32_bf16(afr[m], bfr[3], acc[m][3], 0, 0, 0);
    }

#pragma unroll
    for (int m = 0; m < 4; ++m) idxc[m] = idxn[m];
  }

  // D layout: col = t*16 + (lane&15), row = (lane>>4)*4 + r
#pragma unroll
  for (int m = 0; m < 4; ++m)
#pragma unroll
    for (int t = 0; t < 4; ++t)
#pragma unroll
      for (int r = 0; r < 4; ++r)
        out[(size_t)(row0 + m * 16 + kg * 4 + r) * COUT + t * 16 + c16] = acc[m][t][r];
}

// Correct-but-slow fallback if ws is tiny (shouldn't happen).
__global__ void spconv_naive_kernel(const float* __restrict__ feats,
                                    const float* __restrict__ w,
                                    const float* __restrict__ bias,
                                    const int* __restrict__ in_idx,
                                    float* __restrict__ out) {
  int gid = blockIdx.x * blockDim.x + threadIdx.x;
  if (gid >= NROWS * COUT) return;
  int row = gid / COUT, co = gid % COUT;
  float acc = bias[co];
  for (int k = 0; k < KV; ++k) {
    int idx = in_idx[(size_t)k * NROWS + row];
    if (idx < NROWS) {
      const float* fr = feats + (size_t)idx * CIN;
      const float* wk = w + (size_t)k * CIN * COUT + co;
#pragma unroll
      for (int c = 0; c < CIN; ++c) acc += fr[c] * wk[(size_t)c * COUT];
    }
  }
  out[gid] = acc;
}

extern "C" void kernel_launch(void* const* d_in, const int* in_sizes, int n_in,
                              void* d_out, int out_size, void* d_ws, size_t ws_size,
                              hipStream_t stream) {
  const float* feats  = (const float*)d_in[0];
  const float* weight = (const float*)d_in[1];
  const float* bias   = (const float*)d_in[2];
  const int*   in_idx = (const int*)d_in[3];
  float*       out    = (float*)d_out;

  const size_t wsB_bytes = (size_t)KV * 4 * 64 * 16;        // 110592
  short8* wsB = (short8*)d_ws;

  if (ws_size >= wsB_bytes) {
    prep_weight_kernel<<<27, 256, 0, stream>>>(weight, wsB);
    const int blocks = (NWAVES + 3) / 4;                     // 782
    spconv_mfma_kernel<<<blocks, 256, 0, stream>>>(
        feats, wsB, bias, in_idx, out);
  } else {
    spconv_naive_kernel<<<(NROWS * COUT + 255) / 256, 256, 0, stream>>>(
        feats, weight, bias, in_idx, out);
  }
}

// Round 16
// 54.707 us; speedup vs baseline: 1.5885x; 1.3883x over previous
//
#include <hip/hip_runtime.h>
#include <cstddef>
#include <cstdint>

#define NROWS  200000
#define CIN    32
#define COUT   64
#define KV     27
#define NWAVES (NROWS / 64)   // 3125

typedef __attribute__((ext_vector_type(8))) short  short8;
typedef __attribute__((ext_vector_type(4))) float  f32x4;

// RNE float -> bf16 (inputs finite)
__device__ __forceinline__ unsigned short f2bf(float x) {
  unsigned u = __builtin_bit_cast(unsigned, x);
  u += 0x7FFFu + ((u >> 16) & 1u);
  return (unsigned short)(u >> 16);
}

// Pack weight [27][32][64] f32 -> bf16 B-fragments, mfma_16x16x32 B layout:
// wsB[(k*4+t)*64 + lane][f] = W[k][(lane>>4)*8+f][t*16+(lane&15)]
__global__ void prep_weight_kernel(const float* __restrict__ w,
                                   short8* __restrict__ wsB) {
  int tid = blockIdx.x * blockDim.x + threadIdx.x;   // 27*4*64 = 6912
  if (tid >= KV * 4 * 64) return;
  int lane = tid & 63;
  int t    = (tid >> 6) & 3;
  int k    = tid >> 8;
  int col  = t * 16 + (lane & 15);
  int kin0 = (lane >> 4) * 8;
  short8 v;
#pragma unroll
  for (int f = 0; f < 8; ++f)
    v[f] = (short)f2bf(w[((size_t)k * CIN + kin0 + f) * COUT + col]);
  wsB[tid] = v;
}

// feats f32 [N][32] -> bf16 [N+1][32]; row N (pad) = zeros.
__global__ void prep_feats_kernel(const float* __restrict__ feats,
                                  short8* __restrict__ fb) {
  int i = blockIdx.x * blockDim.x + threadIdx.x;
  const int total8 = (NROWS + 1) * CIN / 8;          // 800004
  if (i >= total8) return;
  short8 v = {0, 0, 0, 0, 0, 0, 0, 0};
  if (i < NROWS * CIN / 8) {
    const f32x4* p = (const f32x4*)feats + (size_t)i * 2;
    f32x4 a = p[0], b = p[1];
#pragma unroll
    for (int f = 0; f < 4; ++f) {
      v[f]     = (short)f2bf(a[f]);
      v[4 + f] = (short)f2bf(b[f]);
    }
  }
  fb[i] = v;
}

// Main: the R5 champion wave VERBATIM (Mw=4, idx staged via LDS, compiler-
// scheduled k-loop, bf16 pre-converted feats) in SINGLE-WAVE 64-thread
// blocks. Rationale: 782 4-wave blocks = only 3.05 blocks/CU of total work
// -> measured 6.7 resident waves/CU; the concurrency deficit is block
// granularity, not wave structure. 3125 single-wave blocks = 12.2/CU with
// fine-grained scheduling; launch_bounds(64,4) admits 16 waves/CU at the
// champion's ~120-reg footprint. Per-wave structure byte-identical to the
// 47us champion -> none of the B/store confounds that sank R8/R13/R14.
__global__ __launch_bounds__(64, 4)
void spconv_mfma_kernel(const unsigned short* __restrict__ featsbf,
                        const short8* __restrict__ wsB,
                        const float* __restrict__ bias,
                        const int* __restrict__ in_idx,
                        float* __restrict__ out) {
  __shared__ int sIdx[KV][64];                       // 6,912 B

  const int lane = threadIdx.x & 63;
  const int wid  = (int)blockIdx.x;
  if (wid >= NWAVES) return;
  const int row0 = wid << 6;

  // ---- stage this wave's idx block into LDS ----
  {
    int tmp[KV];
#pragma unroll
    for (int k = 0; k < KV; ++k)
      tmp[k] = in_idx[(size_t)k * NROWS + row0 + lane];
#pragma unroll
    for (int k = 0; k < KV; ++k)
      sIdx[k][lane] = tmp[k];
  }

  const int c16  = lane & 15;
  const int kg   = lane >> 4;
  const int koff = kg * 8;

  f32x4 acc[4][4];                                   // [m][t]
#pragma unroll
  for (int t = 0; t < 4; ++t) {
    float bv = bias[t * 16 + c16];
    f32x4 bvv = {bv, bv, bv, bv};
#pragma unroll
    for (int m = 0; m < 4; ++m) acc[m][t] = bvv;
  }

  const short8* bp = wsB + lane;

  // idx for k=0 (broadcast ds_read: 4 lanes same address -> free)
  int idxc[4], idxn[4];
#pragma unroll
  for (int m = 0; m < 4; ++m) idxc[m] = sIdx[0][m * 16 + c16];

  for (int k = 0; k < KV; ++k) {
    // prefetch idx(k+1) from LDS (off the global-latency path entirely)
    const int kn = (k + 1 < KV) ? k + 1 : KV - 1;
#pragma unroll
    for (int m = 0; m < 4; ++m) idxn[m] = sIdx[kn][m * 16 + c16];

    short8 bfr[4];
#pragma unroll
    for (int t = 0; t < 4; ++t) bfr[t] = bp[(k * 4 + t) * 64];

    short8 afr[4];
#pragma unroll
    for (int m = 0; m < 4; ++m)
      afr[m] = *(const short8*)(featsbf + (size_t)idxc[m] * CIN + koff);

#pragma unroll
    for (int m = 0; m < 4; ++m) {
      acc[m][0] = __builtin_amdgcn_mfma_f32_16x16x32_bf16(afr[m], bfr[0], acc[m][0], 0, 0, 0);
      acc[m][1] = __builtin_amdgcn_mfma_f32_16x16x32_bf16(afr[m], bfr[1], acc[m][1], 0, 0, 0);
      acc[m][2] = __builtin_amdgcn_mfma_f32_16x16x32_bf16(afr[m], bfr[2], acc[m][2], 0, 0, 0);
      acc[m][3] = __builtin_amdgcn_mfma_f32_16x16x32_bf16(afr[m], bfr[3], acc[m][3], 0, 0, 0);
    }

#pragma unroll
    for (int m = 0; m < 4; ++m) idxc[m] = idxn[m];
  }

  // D layout: col = t*16 + (lane&15), row = (lane>>4)*4 + r
#pragma unroll
  for (int m = 0; m < 4; ++m)
#pragma unroll
    for (int t = 0; t < 4; ++t)
#pragma unroll
      for (int r = 0; r < 4; ++r)
        out[(size_t)(row0 + m * 16 + kg * 4 + r) * COUT + t * 16 + c16] = acc[m][t][r];
}

// Correct-but-slow fallback if ws is tiny (shouldn't happen).
__global__ void spconv_naive_kernel(const float* __restrict__ feats,
                                    const float* __restrict__ w,
                                    const float* __restrict__ bias,
                                    const int* __restrict__ in_idx,
                                    float* __restrict__ out) {
  int gid = blockIdx.x * blockDim.x + threadIdx.x;
  if (gid >= NROWS * COUT) return;
  int row = gid / COUT, co = gid % COUT;
  float acc = bias[co];
  for (int k = 0; k < KV; ++k) {
    int idx = in_idx[(size_t)k * NROWS + row];
    if (idx < NROWS) {
      const float* fr = feats + (size_t)idx * CIN;
      const float* wk = w + (size_t)k * CIN * COUT + co;
#pragma unroll
      for (int c = 0; c < CIN; ++c) acc += fr[c] * wk[(size_t)c * COUT];
    }
  }
  out[gid] = acc;
}

extern "C" void kernel_launch(void* const* d_in, const int* in_sizes, int n_in,
                              void* d_out, int out_size, void* d_ws, size_t ws_size,
                              hipStream_t stream) {
  const float* feats  = (const float*)d_in[0];
  const float* weight = (const float*)d_in[1];
  const float* bias   = (const float*)d_in[2];
  const int*   in_idx = (const int*)d_in[3];
  float*       out    = (float*)d_out;

  const size_t wsB_bytes = (size_t)KV * 4 * 64 * 16;        // 110592
  const size_t fb_bytes  = (size_t)(NROWS + 1) * CIN * 2;   // 12800064
  short8*         wsB     = (short8*)d_ws;
  unsigned short* featsbf = (unsigned short*)((char*)d_ws + wsB_bytes);

  if (ws_size >= wsB_bytes + fb_bytes) {
    prep_weight_kernel<<<27, 256, 0, stream>>>(weight, wsB);
    prep_feats_kernel<<<((NROWS + 1) * CIN / 8 + 255) / 256, 256, 0, stream>>>(
        feats, (short8*)featsbf);
    spconv_mfma_kernel<<<NWAVES, 64, 0, stream>>>(
        featsbf, wsB, bias, in_idx, out);
  } else {
    spconv_naive_kernel<<<(NROWS * COUT + 255) / 256, 256, 0, stream>>>(
        feats, weight, bias, in_idx, out);
  }
}

// Round 17
// 50.997 us; speedup vs baseline: 1.7040x; 1.0728x over previous
//
#include <hip/hip_runtime.h>
#include <cstddef>
#include <cstdint>

#define NROWS  200000
#define CIN    32
#define COUT   64
#define KV     27
#define NWAVES (NROWS / 64)   // 3125

typedef __attribute__((ext_vector_type(8))) short  short8;
typedef __attribute__((ext_vector_type(4))) float  f32x4;

// RNE float -> bf16 (inputs finite)
__device__ __forceinline__ unsigned short f2bf(float x) {
  unsigned u = __builtin_bit_cast(unsigned, x);
  u += 0x7FFFu + ((u >> 16) & 1u);
  return (unsigned short)(u >> 16);
}

// Fused prep: blocks [0,27) pack weight -> bf16 B-fragments in ws;
// blocks [27, 27+3126) convert feats f32 -> bf16 (pad row N = zeros).
// One launch instead of two (saves a launch gap ~2-3 us).
__global__ void prep_fused_kernel(const float* __restrict__ w,
                                  const float* __restrict__ feats,
                                  short8* __restrict__ wsB,
                                  short8* __restrict__ fb) {
  const int bid = blockIdx.x;
  const int tid = threadIdx.x;
  if (bid < 27) {
    // weight pack: wsB[(k*4+t)*64+lane][f] = W[k][(lane>>4)*8+f][t*16+(lane&15)]
    int gid = bid * 256 + tid;                       // 6912 total
    int lane = gid & 63;
    int t    = (gid >> 6) & 3;
    int k    = gid >> 8;
    int col  = t * 16 + (lane & 15);
    int kin0 = (lane >> 4) * 8;
    short8 v;
#pragma unroll
    for (int f = 0; f < 8; ++f)
      v[f] = (short)f2bf(w[((size_t)k * CIN + kin0 + f) * COUT + col]);
    wsB[gid] = v;
  } else {
    int i = (bid - 27) * 256 + tid;                  // short8 units
    const int total8 = (NROWS + 1) * CIN / 8;        // 800004
    if (i >= total8) return;
    short8 v = {0, 0, 0, 0, 0, 0, 0, 0};
    if (i < NROWS * CIN / 8) {
      const f32x4* p = (const f32x4*)feats + (size_t)i * 2;
      f32x4 a = p[0], b = p[1];
#pragma unroll
      for (int f = 0; f < 4; ++f) {
        v[f]     = (short)f2bf(a[f]);
        v[4 + f] = (short)f2bf(b[f]);
      }
    }
    fb[i] = v;
  }
}

// Main: R16 champion (Mw=4 wave, idx staged via LDS, single-wave 64-thread
// blocks, compiler-scheduled k-loop) + s_setprio(1) around the MFMA cluster.
// setprio rationale: independent 1-wave blocks sit at different k-phases on
// each SIMD (the exact regime where setprio measured +4-7% in the guide's
// attn A/B); prioritizing the MFMA-entering wave keeps the matrix pipe fed
// while sibling waves issue gathers.
__global__ __launch_bounds__(64, 4)
void spconv_mfma_kernel(const unsigned short* __restrict__ featsbf,
                        const short8* __restrict__ wsB,
                        const float* __restrict__ bias,
                        const int* __restrict__ in_idx,
                        float* __restrict__ out) {
  __shared__ int sIdx[KV][64];                       // 6,912 B

  const int lane = threadIdx.x & 63;
  const int wid  = (int)blockIdx.x;
  if (wid >= NWAVES) return;
  const int row0 = wid << 6;

  // ---- stage this wave's idx block into LDS ----
  {
    int tmp[KV];
#pragma unroll
    for (int k = 0; k < KV; ++k)
      tmp[k] = in_idx[(size_t)k * NROWS + row0 + lane];
#pragma unroll
    for (int k = 0; k < KV; ++k)
      sIdx[k][lane] = tmp[k];
  }

  const int c16  = lane & 15;
  const int kg   = lane >> 4;
  const int koff = kg * 8;

  f32x4 acc[4][4];                                   // [m][t]
#pragma unroll
  for (int t = 0; t < 4; ++t) {
    float bv = bias[t * 16 + c16];
    f32x4 bvv = {bv, bv, bv, bv};
#pragma unroll
    for (int m = 0; m < 4; ++m) acc[m][t] = bvv;
  }

  const short8* bp = wsB + lane;

  // idx for k=0 (broadcast ds_read: 4 lanes same address -> free)
  int idxc[4], idxn[4];
#pragma unroll
  for (int m = 0; m < 4; ++m) idxc[m] = sIdx[0][m * 16 + c16];

  for (int k = 0; k < KV; ++k) {
    // prefetch idx(k+1) from LDS (off the global-latency path entirely)
    const int kn = (k + 1 < KV) ? k + 1 : KV - 1;
#pragma unroll
    for (int m = 0; m < 4; ++m) idxn[m] = sIdx[kn][m * 16 + c16];

    short8 bfr[4];
#pragma unroll
    for (int t = 0; t < 4; ++t) bfr[t] = bp[(k * 4 + t) * 64];

    short8 afr[4];
#pragma unroll
    for (int m = 0; m < 4; ++m)
      afr[m] = *(const short8*)(featsbf + (size_t)idxc[m] * CIN + koff);

    __builtin_amdgcn_s_setprio(1);
#pragma unroll
    for (int m = 0; m < 4; ++m) {
      acc[m][0] = __builtin_amdgcn_mfma_f32_16x16x32_bf16(afr[m], bfr[0], acc[m][0], 0, 0, 0);
      acc[m][1] = __builtin_amdgcn_mfma_f32_16x16x32_bf16(afr[m], bfr[1], acc[m][1], 0, 0, 0);
      acc[m][2] = __builtin_amdgcn_mfma_f32_16x16x32_bf16(afr[m], bfr[2], acc[m][2], 0, 0, 0);
      acc[m][3] = __builtin_amdgcn_mfma_f32_16x16x32_bf16(afr[m], bfr[3], acc[m][3], 0, 0, 0);
    }
    __builtin_amdgcn_s_setprio(0);

#pragma unroll
    for (int m = 0; m < 4; ++m) idxc[m] = idxn[m];
  }

  // D layout: col = t*16 + (lane&15), row = (lane>>4)*4 + r
#pragma unroll
  for (int m = 0; m < 4; ++m)
#pragma unroll
    for (int t = 0; t < 4; ++t)
#pragma unroll
      for (int r = 0; r < 4; ++r)
        out[(size_t)(row0 + m * 16 + kg * 4 + r) * COUT + t * 16 + c16] = acc[m][t][r];
}

// Correct-but-slow fallback if ws is tiny (shouldn't happen).
__global__ void spconv_naive_kernel(const float* __restrict__ feats,
                                    const float* __restrict__ w,
                                    const float* __restrict__ bias,
                                    const int* __restrict__ in_idx,
                                    float* __restrict__ out) {
  int gid = blockIdx.x * blockDim.x + threadIdx.x;
  if (gid >= NROWS * COUT) return;
  int row = gid / COUT, co = gid % COUT;
  float acc = bias[co];
  for (int k = 0; k < KV; ++k) {
    int idx = in_idx[(size_t)k * NROWS + row];
    if (idx < NROWS) {
      const float* fr = feats + (size_t)idx * CIN;
      const float* wk = w + (size_t)k * CIN * COUT + co;
#pragma unroll
      for (int c = 0; c < CIN; ++c) acc += fr[c] * wk[(size_t)c * COUT];
    }
  }
  out[gid] = acc;
}

extern "C" void kernel_launch(void* const* d_in, const int* in_sizes, int n_in,
                              void* d_out, int out_size, void* d_ws, size_t ws_size,
                              hipStream_t stream) {
  const float* feats  = (const float*)d_in[0];
  const float* weight = (const float*)d_in[1];
  const float* bias   = (const float*)d_in[2];
  const int*   in_idx = (const int*)d_in[3];
  float*       out    = (float*)d_out;

  const size_t wsB_bytes = (size_t)KV * 4 * 64 * 16;        // 110592
  const size_t fb_bytes  = (size_t)(NROWS + 1) * CIN * 2;   // 12800064
  short8*         wsB     = (short8*)d_ws;
  unsigned short* featsbf = (unsigned short*)((char*)d_ws + wsB_bytes);

  if (ws_size >= wsB_bytes + fb_bytes) {
    const int prepBlocks = 27 + ((NROWS + 1) * CIN / 8 + 255) / 256;  // 3153
    prep_fused_kernel<<<prepBlocks, 256, 0, stream>>>(
        weight, feats, wsB, (short8*)featsbf);
    spconv_mfma_kernel<<<NWAVES, 64, 0, stream>>>(
        featsbf, wsB, bias, in_idx, out);
  } else {
    spconv_naive_kernel<<<(NROWS * COUT + 255) / 256, 256, 0, stream>>>(
        feats, weight, bias, in_idx, out);
  }
}

// Round 18
// 49.558 us; speedup vs baseline: 1.7535x; 1.0290x over previous
//
#include <hip/hip_runtime.h>
#include <cstddef>
#include <cstdint>

#define NROWS  200000
#define CIN    32
#define COUT   64
#define KV     27
#define NWAVES (NROWS / 64)   // 3125

typedef __attribute__((ext_vector_type(8))) short  short8;
typedef __attribute__((ext_vector_type(4))) float  f32x4;

// RNE float -> bf16 (inputs finite)
__device__ __forceinline__ unsigned short f2bf(float x) {
  unsigned u = __builtin_bit_cast(unsigned, x);
  u += 0x7FFFu + ((u >> 16) & 1u);
  return (unsigned short)(u >> 16);
}

// Fused prep: blocks [0,27) pack weight -> bf16 B-fragments in ws;
// blocks [27, 27+3126) convert feats f32 -> bf16 (pad row N = zeros).
// One launch instead of two (R17: -3.7 us total).
__global__ void prep_fused_kernel(const float* __restrict__ w,
                                  const float* __restrict__ feats,
                                  short8* __restrict__ wsB,
                                  short8* __restrict__ fb) {
  const int bid = blockIdx.x;
  const int tid = threadIdx.x;
  if (bid < 27) {
    // weight pack: wsB[(k*4+t)*64+lane][f] = W[k][(lane>>4)*8+f][t*16+(lane&15)]
    int gid = bid * 256 + tid;                       // 6912 total
    int lane = gid & 63;
    int t    = (gid >> 6) & 3;
    int k    = gid >> 8;
    int col  = t * 16 + (lane & 15);
    int kin0 = (lane >> 4) * 8;
    short8 v;
#pragma unroll
    for (int f = 0; f < 8; ++f)
      v[f] = (short)f2bf(w[((size_t)k * CIN + kin0 + f) * COUT + col]);
    wsB[gid] = v;
  } else {
    int i = (bid - 27) * 256 + tid;                  // short8 units
    const int total8 = (NROWS + 1) * CIN / 8;        // 800004
    if (i >= total8) return;
    short8 v = {0, 0, 0, 0, 0, 0, 0, 0};
    if (i < NROWS * CIN / 8) {
      const f32x4* p = (const f32x4*)feats + (size_t)i * 2;
      f32x4 a = p[0], b = p[1];
#pragma unroll
      for (int f = 0; f < 4; ++f) {
        v[f]     = (short)f2bf(a[f]);
        v[4 + f] = (short)f2bf(b[f]);
      }
    }
    fb[i] = v;
  }
}

// Main: R16 champion VERBATIM (Mw=4 wave, idx staged via LDS, single-wave
// 64-thread blocks, compiler-scheduled k-loop). setprio REMOVED: R17 A/B
// showed +6% main-kernel regression (prio-1 MFMA waves starve siblings'
// gather issue; this kernel lives on gather issue rate).
__global__ __launch_bounds__(64, 4)
void spconv_mfma_kernel(const unsigned short* __restrict__ featsbf,
                        const short8* __restrict__ wsB,
                        const float* __restrict__ bias,
                        const int* __restrict__ in_idx,
                        float* __restrict__ out) {
  __shared__ int sIdx[KV][64];                       // 6,912 B

  const int lane = threadIdx.x & 63;
  const int wid  = (int)blockIdx.x;
  if (wid >= NWAVES) return;
  const int row0 = wid << 6;

  // ---- stage this wave's idx block into LDS ----
  {
    int tmp[KV];
#pragma unroll
    for (int k = 0; k < KV; ++k)
      tmp[k] = in_idx[(size_t)k * NROWS + row0 + lane];
#pragma unroll
    for (int k = 0; k < KV; ++k)
      sIdx[k][lane] = tmp[k];
  }

  const int c16  = lane & 15;
  const int kg   = lane >> 4;
  const int koff = kg * 8;

  f32x4 acc[4][4];                                   // [m][t]
#pragma unroll
  for (int t = 0; t < 4; ++t) {
    float bv = bias[t * 16 + c16];
    f32x4 bvv = {bv, bv, bv, bv};
#pragma unroll
    for (int m = 0; m < 4; ++m) acc[m][t] = bvv;
  }

  const short8* bp = wsB + lane;

  // idx for k=0 (broadcast ds_read: 4 lanes same address -> free)
  int idxc[4], idxn[4];
#pragma unroll
  for (int m = 0; m < 4; ++m) idxc[m] = sIdx[0][m * 16 + c16];

  for (int k = 0; k < KV; ++k) {
    // prefetch idx(k+1) from LDS (off the global-latency path entirely)
    const int kn = (k + 1 < KV) ? k + 1 : KV - 1;
#pragma unroll
    for (int m = 0; m < 4; ++m) idxn[m] = sIdx[kn][m * 16 + c16];

    short8 bfr[4];
#pragma unroll
    for (int t = 0; t < 4; ++t) bfr[t] = bp[(k * 4 + t) * 64];

    short8 afr[4];
#pragma unroll
    for (int m = 0; m < 4; ++m)
      afr[m] = *(const short8*)(featsbf + (size_t)idxc[m] * CIN + koff);

#pragma unroll
    for (int m = 0; m < 4; ++m) {
      acc[m][0] = __builtin_amdgcn_mfma_f32_16x16x32_bf16(afr[m], bfr[0], acc[m][0], 0, 0, 0);
      acc[m][1] = __builtin_amdgcn_mfma_f32_16x16x32_bf16(afr[m], bfr[1], acc[m][1], 0, 0, 0);
      acc[m][2] = __builtin_amdgcn_mfma_f32_16x16x32_bf16(afr[m], bfr[2], acc[m][2], 0, 0, 0);
      acc[m][3] = __builtin_amdgcn_mfma_f32_16x16x32_bf16(afr[m], bfr[3], acc[m][3], 0, 0, 0);
    }

#pragma unroll
    for (int m = 0; m < 4; ++m) idxc[m] = idxn[m];
  }

  // D layout: col = t*16 + (lane&15), row = (lane>>4)*4 + r
#pragma unroll
  for (int m = 0; m < 4; ++m)
#pragma unroll
    for (int t = 0; t < 4; ++t)
#pragma unroll
      for (int r = 0; r < 4; ++r)
        out[(size_t)(row0 + m * 16 + kg * 4 + r) * COUT + t * 16 + c16] = acc[m][t][r];
}

// Correct-but-slow fallback if ws is tiny (shouldn't happen).
__global__ void spconv_naive_kernel(const float* __restrict__ feats,
                                    const float* __restrict__ w,
                                    const float* __restrict__ bias,
                                    const int* __restrict__ in_idx,
                                    float* __restrict__ out) {
  int gid = blockIdx.x * blockDim.x + threadIdx.x;
  if (gid >= NROWS * COUT) return;
  int row = gid / COUT, co = gid % COUT;
  float acc = bias[co];
  for (int k = 0; k < KV; ++k) {
    int idx = in_idx[(size_t)k * NROWS + row];
    if (idx < NROWS) {
      const float* fr = feats + (size_t)idx * CIN;
      const float* wk = w + (size_t)k * CIN * COUT + co;
#pragma unroll
      for (int c = 0; c < CIN; ++c) acc += fr[c] * wk[(size_t)c * COUT];
    }
  }
  out[gid] = acc;
}

extern "C" void kernel_launch(void* const* d_in, const int* in_sizes, int n_in,
                              void* d_out, int out_size, void* d_ws, size_t ws_size,
                              hipStream_t stream) {
  const float* feats  = (const float*)d_in[0];
  const float* weight = (const float*)d_in[1];
  const float* bias   = (const float*)d_in[2];
  const int*   in_idx = (const int*)d_in[3];
  float*       out    = (float*)d_out;

  const size_t wsB_bytes = (size_t)KV * 4 * 64 * 16;        // 110592
  const size_t fb_bytes  = (size_t)(NROWS + 1) * CIN * 2;   // 12800064
  short8*         wsB     = (short8*)d_ws;
  unsigned short* featsbf = (unsigned short*)((char*)d_ws + wsB_bytes);

  if (ws_size >= wsB_bytes + fb_bytes) {
    const int prepBlocks = 27 + ((NROWS + 1) * CIN / 8 + 255) / 256;  // 3153
    prep_fused_kernel<<<prepBlocks, 256, 0, stream>>>(
        weight, feats, wsB, (short8*)featsbf);
    spconv_mfma_kernel<<<NWAVES, 64, 0, stream>>>(
        featsbf, wsB, bias, in_idx, out);
  } else {
    spconv_naive_kernel<<<(NROWS * COUT + 255) / 256, 256, 0, stream>>>(
        feats, weight, bias, in_idx, out);
  }
}